// Round 11
// baseline (95.574 us; speedup 1.0000x reference)
//
#include <hip/hip_runtime.h>
#include <stdint.h>

typedef unsigned short u16;
typedef __attribute__((ext_vector_type(8))) __bf16 bf16x8;
typedef __attribute__((ext_vector_type(4))) float f32x4;
typedef __attribute__((ext_vector_type(16))) float f32x16;

#define D_IN 1024
#define NH 16
#define DH 64
#define BATCH 2
#define SEQ 2048

// log2(e)/sqrt(64): folded into Q at the QKV-projection epilogue so the
// attention kernel can use v_exp_f32 (2^x) directly with NO per-score scaling.
#define QSCL 0.1803368801111244f

#define GLD_LDS16(gp, lp)                                                              \
  __builtin_amdgcn_global_load_lds((__attribute__((address_space(1))) const void*)(gp), \
                                   (__attribute__((address_space(3))) void*)(lp), 16, 0, 0)

__device__ __forceinline__ u16 f2b(float f) {
  union { float ff; uint32_t u; } v; v.ff = f;
  return (u16)((v.u + 0x7fffu + ((v.u >> 16) & 1u)) >> 16);
}

__device__ __forceinline__ float swap32f(float v) { return __shfl_xor(v, 32, 64); }

__device__ __forceinline__ uint32_t cvtpk(float a, float b) {
  uint32_t r;
  asm("v_cvt_pk_bf16_f32 %0, %1, %2" : "=v"(r) : "v"(a), "v"(b));
  return r;
}
__device__ __forceinline__ float fexp2(float x) {
  float r;
  asm("v_exp_f32 %0, %1" : "=v"(r) : "v"(x));
  return r;
}

// ---------------- 1) fused prep: x->bf16  +  W->W^T bf16 ----------------
__global__ __launch_bounds__(256)
void prep_kernel(const float* __restrict__ x, u16* __restrict__ xb,
                 const float* __restrict__ W0, const float* __restrict__ W1,
                 const float* __restrict__ W2, const float* __restrict__ W3,
                 u16* __restrict__ T0, u16* __restrict__ T1,
                 u16* __restrict__ T2, u16* __restrict__ T3) {
  __shared__ float tile[32][33];
  if (blockIdx.x < 4096) {
    const int i = (blockIdx.x * 256 + threadIdx.x) * 4;
    const float4 v = *(const float4*)(x + i);
    uint2 pack;
    pack.x = (uint32_t)f2b(v.x) | ((uint32_t)f2b(v.y) << 16);
    pack.y = (uint32_t)f2b(v.z) | ((uint32_t)f2b(v.w) << 16);
    *(uint2*)(xb + i) = pack;
  } else {
    const int bid2 = blockIdx.x - 4096;
    const float* W; u16* T;
    switch (bid2 >> 10) {
      case 0: W = W0; T = T0; break;
      case 1: W = W1; T = T1; break;
      case 2: W = W2; T = T2; break;
      default: W = W3; T = T3; break;
    }
    const int rem = bid2 & 1023;
    const int n0 = (rem >> 5) * 32, k0 = (rem & 31) * 32;
    const int tx = threadIdx.x & 31, ty = threadIdx.x >> 5;
    #pragma unroll
    for (int i = 0; i < 32; i += 8)
      tile[ty + i][tx] = W[(size_t)(k0 + ty + i) * D_IN + n0 + tx];
    __syncthreads();
    #pragma unroll
    for (int i = 0; i < 32; i += 8)
      T[(size_t)(n0 + ty + i) * D_IN + k0 + tx] = f2b(tile[tx][ty + i]);
  }
}

// ---------------- 2) FUSED QKV projection GEMM (r10, unchanged) ----------------
__device__ __forceinline__ void qkv_compute(
    const u16* __restrict__ AsB, const u16* __restrict__ Bq,
    const u16* __restrict__ Bk, const u16* __restrict__ Bv,
    int wm, int wn, int g, int lm,
    f32x4 accq[4][2], f32x4 acck[4][2], f32x4 accv[4][2]) {
  #pragma unroll
  for (int kk = 0; kk < 2; ++kk) {
    const int slot = ((kk * 4 + g) ^ (lm & 7)) << 3;
    bf16x8 af[4];
    #pragma unroll
    for (int i = 0; i < 4; ++i)
      af[i] = *(const bf16x8*)(AsB + (wm * 64 + i * 16 + lm) * 64 + slot);
    bf16x8 bq[2], bk[2], bv[2];
    #pragma unroll
    for (int n = 0; n < 2; ++n) {
      const int ro = (wn * 32 + n * 16 + lm) * 64 + slot;
      bq[n] = *(const bf16x8*)(Bq + ro);
      bk[n] = *(const bf16x8*)(Bk + ro);
      bv[n] = *(const bf16x8*)(Bv + ro);
    }
    #pragma unroll
    for (int i = 0; i < 4; ++i)
      #pragma unroll
      for (int n = 0; n < 2; ++n) {
        accq[i][n] = __builtin_amdgcn_mfma_f32_16x16x32_bf16(af[i], bq[n], accq[i][n], 0, 0, 0);
        acck[i][n] = __builtin_amdgcn_mfma_f32_16x16x32_bf16(af[i], bk[n], acck[i][n], 0, 0, 0);
        accv[i][n] = __builtin_amdgcn_mfma_f32_16x16x32_bf16(af[i], bv[n], accv[i][n], 0, 0, 0);
      }
  }
}

__global__ __launch_bounds__(512)
void gemm_qkv_kernel(const u16* __restrict__ Xb,
                     const u16* __restrict__ WqT, const u16* __restrict__ WkT,
                     const u16* __restrict__ WvT,
                     u16* __restrict__ Qo, u16* __restrict__ Ko, u16* __restrict__ Vt) {
  __shared__ u16 As[2][128 * 64];     // 32 KB
  __shared__ u16 Bs[2][3][128 * 64];  // 96 KB

  const int tid = threadIdx.x;
  const int lane = tid & 63;
  const int w = tid >> 6;            // 0..7
  const int wm = w >> 2, wn = w & 3; // wave tile 64x32 per which
  const int bm = blockIdx.x * 128;
  const int bn = blockIdx.y * 128;
  const int g = lane >> 4, lm = lane & 15;

  const int r_in = lane >> 3;
  const int s_w = lane & 7;
  const int swz_col = (s_w ^ r_in) << 3;

  const int c0 = w * 2;  // this wave's chunk base (2 chunks of 8 rows each)
  const u16* a_src0 = Xb + (size_t)(bm + c0 * 8 + r_in) * D_IN + swz_col;
  const u16* a_src1 = a_src0 + 8 * D_IN;
  const u16* q_src0 = WqT + (size_t)(bn + c0 * 8 + r_in) * D_IN + swz_col;
  const u16* q_src1 = q_src0 + 8 * D_IN;
  const u16* k_src0 = WkT + (size_t)(bn + c0 * 8 + r_in) * D_IN + swz_col;
  const u16* k_src1 = k_src0 + 8 * D_IN;
  const u16* v_src0 = WvT + (size_t)(bn + c0 * 8 + r_in) * D_IN + swz_col;
  const u16* v_src1 = v_src0 + 8 * D_IN;

#define QKV_STAGE(BUF, K0)                                 \
  do {                                                     \
    GLD_LDS16(a_src0 + (K0), &As[BUF][c0 * 512]);          \
    GLD_LDS16(a_src1 + (K0), &As[BUF][c0 * 512 + 512]);    \
    GLD_LDS16(q_src0 + (K0), &Bs[BUF][0][c0 * 512]);       \
    GLD_LDS16(q_src1 + (K0), &Bs[BUF][0][c0 * 512 + 512]); \
    GLD_LDS16(k_src0 + (K0), &Bs[BUF][1][c0 * 512]);       \
    GLD_LDS16(k_src1 + (K0), &Bs[BUF][1][c0 * 512 + 512]); \
    GLD_LDS16(v_src0 + (K0), &Bs[BUF][2][c0 * 512]);       \
    GLD_LDS16(v_src1 + (K0), &Bs[BUF][2][c0 * 512 + 512]); \
  } while (0)

  f32x4 accq[4][2], acck[4][2], accv[4][2];
  #pragma unroll
  for (int i = 0; i < 4; ++i)
    #pragma unroll
    for (int n = 0; n < 2; ++n) {
      accq[i][n] = {0.f, 0.f, 0.f, 0.f};
      acck[i][n] = {0.f, 0.f, 0.f, 0.f};
      accv[i][n] = {0.f, 0.f, 0.f, 0.f};
    }

  QKV_STAGE(0, 0);
  QKV_STAGE(1, 64);
  #pragma unroll 1
  for (int tt = 0; tt < 7; ++tt) {
    asm volatile("s_waitcnt vmcnt(8)" ::: "memory");
    __builtin_amdgcn_s_barrier();
    qkv_compute(As[0], Bs[0][0], Bs[0][1], Bs[0][2], wm, wn, g, lm, accq, acck, accv);
    __builtin_amdgcn_s_barrier();
    QKV_STAGE(0, (2 * tt + 2) * 64);
    asm volatile("s_waitcnt vmcnt(8)" ::: "memory");
    __builtin_amdgcn_s_barrier();
    qkv_compute(As[1], Bs[1][0], Bs[1][1], Bs[1][2], wm, wn, g, lm, accq, acck, accv);
    __builtin_amdgcn_s_barrier();
    QKV_STAGE(1, (2 * tt + 3) * 64);
  }
  asm volatile("s_waitcnt vmcnt(8)" ::: "memory");
  __builtin_amdgcn_s_barrier();
  qkv_compute(As[0], Bs[0][0], Bs[0][1], Bs[0][2], wm, wn, g, lm, accq, acck, accv);  // t=14
  asm volatile("s_waitcnt vmcnt(0)" ::: "memory");
  __builtin_amdgcn_s_barrier();
  qkv_compute(As[1], Bs[1][0], Bs[1][1], Bs[1][2], wm, wn, g, lm, accq, acck, accv);  // t=15
#undef QKV_STAGE

  // epilogue: scatter Q (scaled), K, V(fragment-permuted) -- r6-verified index math
  #pragma unroll
  for (int i = 0; i < 4; ++i) {
    #pragma unroll
    for (int n = 0; n < 2; ++n) {
      #pragma unroll
      for (int r = 0; r < 4; ++r) {
        const int m = bm + wm * 64 + i * 16 + g * 4 + r;
        const int c = bn + wn * 32 + n * 16 + lm;
        const int b = m >> 11, nn = m & (SEQ - 1);
        const int h = c >> 6, d = c & (DH - 1);
        const int bh = b * NH + h;
        const int t = nn >> 5;
        {
          const u16 val = f2b(accq[i][n][r] * QSCL);
          const int st = d >> 4;
          const int lane2 = ((d >> 3) & 1) * 32 + (nn & 31);
          const int j = d & 7;
          Qo[((size_t)(bh * 64 + t) * 4 + st) * 512 + lane2 * 8 + j] = val;
        }
        {
          const u16 val = f2b(acck[i][n][r]);
          const int st = d >> 4;
          const int lane2 = ((d >> 3) & 1) * 32 + (nn & 31);
          const int j = d & 7;
          Ko[((size_t)(bh * 64 + t) * 4 + st) * 512 + lane2 * 8 + j] = val;
        }
        {
          const u16 val = f2b(accv[i][n][r]);
          const int n5 = nn & 31;
          const int f = (n5 >> 4) * 2 + (d >> 5);
          const int lane2 = ((n5 >> 2) & 1) * 32 + (d & 31);
          const int j = ((n5 >> 3) & 1) * 4 + (n5 & 3);
          Vt[((size_t)(bh * 64 + t) * 4 + f) * 512 + lane2 * 8 + j] = val;
        }
      }
    }
  }
}

// ---------------- 3) causal flash attention: paired q-subtiles per K/V fetch ----------------
// 512 blocks x 256 thr (4 waves). Block (bh, sp) processes q-group {2sp,2sp+1}
// then {62-2sp,63-2sp}: adjacent subtiles share the causal k-range, so each
// fetched K/V tile feeds TWO q-subtiles -> L2 read traffic HALVES (532->270 MB;
// r10's attn was L2-BW-bound at ~15us wall). Per-block work constant: 66
// fetches, 130 subtile-steps. k split 4-way (mod 4) across waves; fixed softmax
// max (=0); 4-way split-k merge per subtile via LDS. bid%8==head%8 XCD-pins K/V.
__global__ __launch_bounds__(256)
void attn5_kernel(const u16* __restrict__ Qb, const u16* __restrict__ Kb,
                  const u16* __restrict__ Vt, u16* __restrict__ Ctx) {
  __shared__ float mbuf[4][2][32][64];   // [wave][subtile][q][d], chunk-XOR-swizzled
  __shared__ float lbuf[4][2][32];

  const int tid = threadIdx.x;
  const int lane = tid & 63;
  const int kw = tid >> 6;             // wave = split-k slot 0..3
  const int ql = lane & 31;
  const int hi = lane >> 5;
  const int bid = blockIdx.x;
  const int c = bid & 7;
  const int r = bid >> 3;              // 0..63
  const int sp = r & 15;               // group-pair index
  const int bh = c + 8 * (r >> 4);     // 0..31
  const int b = bh >> 4, h = bh & 15;

  const u16* Qf = Qb + (size_t)bh * 64 * 2048;
  const u16* Kf = Kb + (size_t)bh * 64 * 2048;
  const u16* Vf = Vt + (size_t)bh * 64 * 2048;
  const int lofs = lane * 8;

  #pragma unroll 1
  for (int pass = 0; pass < 2; ++pass) {
    const int g0 = pass ? (62 - 2 * sp) : (2 * sp);  // lower q-tile of group
    const int g1 = g0 + 1;                           // upper q-tile (k limit)

    bf16x8 qfA[4], qfB[4];
    {
      const u16* qpA = Qf + (size_t)g0 * 2048 + lofs;
      const u16* qpB = Qf + (size_t)g1 * 2048 + lofs;
      #pragma unroll
      for (int st = 0; st < 4; ++st) {
        qfA[st] = *(const bf16x8*)(qpA + st * 512);
        qfB[st] = *(const bf16x8*)(qpB + st * 512);
      }
    }

    f32x16 cA0 = {0,0,0,0,0,0,0,0,0,0,0,0,0,0,0,0};
    f32x16 cA1 = {0,0,0,0,0,0,0,0,0,0,0,0,0,0,0,0};
    f32x16 cB0 = {0,0,0,0,0,0,0,0,0,0,0,0,0,0,0,0};
    f32x16 cB1 = {0,0,0,0,0,0,0,0,0,0,0,0,0,0,0,0};
    float lA[4] = {0.f, 0.f, 0.f, 0.f};
    float lB[4] = {0.f, 0.f, 0.f, 0.f};

    bf16x8 kf[4], vf[4];
    if (kw <= g1) {
      {
        const u16* kp = Kf + (size_t)kw * 2048 + lofs;
        const u16* vp = Vf + (size_t)kw * 2048 + lofs;
        #pragma unroll
        for (int st = 0; st < 4; ++st) kf[st] = *(const bf16x8*)(kp + st * 512);
        #pragma unroll
        for (int f = 0; f < 4; ++f) vf[f] = *(const bf16x8*)(vp + f * 512);
      }
      #pragma unroll 1
      for (int t = kw; t <= g1; t += 4) {
        const int tn = (t + 4 <= g1) ? (t + 4) : g1;
        const bool doA = (t <= g0);

        // ---- subtile B (q-tile g1): always active in range ----
        {
          f32x16 s = {0,0,0,0,0,0,0,0,0,0,0,0,0,0,0,0};
          #pragma unroll
          for (int st = 0; st < 4; ++st)
            s = __builtin_amdgcn_mfma_f32_32x32x16_bf16(kf[st], qfB[st], s, 0, 0, 0);
          float p[16];
          if (t == g1) {
            #pragma unroll
            for (int cr = 0; cr < 16; ++cr) {
              const int kl = ((cr & 3) + 8 * (cr >> 2)) + 4 * hi;
              p[cr] = (kl > ql) ? 0.f : fexp2(s[cr]);
            }
          } else {
            #pragma unroll
            for (int cr = 0; cr < 16; ++cr) p[cr] = fexp2(s[cr]);
          }
          #pragma unroll
          for (int cr = 0; cr < 16; ++cr) lB[cr & 3] += p[cr];
          #pragma unroll
          for (int ks = 0; ks < 2; ++ks) {
            uint4 pw;
            pw.x = cvtpk(p[ks * 8 + 0], p[ks * 8 + 1]);
            pw.y = cvtpk(p[ks * 8 + 2], p[ks * 8 + 3]);
            pw.z = cvtpk(p[ks * 8 + 4], p[ks * 8 + 5]);
            pw.w = cvtpk(p[ks * 8 + 6], p[ks * 8 + 7]);
            union { uint4 u; bf16x8 v; } pa; pa.u = pw;
            cB0 = __builtin_amdgcn_mfma_f32_32x32x16_bf16(vf[ks * 2 + 0], pa.v, cB0, 0, 0, 0);
            cB1 = __builtin_amdgcn_mfma_f32_32x32x16_bf16(vf[ks * 2 + 1], pa.v, cB1, 0, 0, 0);
          }
        }

        // ---- subtile A (q-tile g0): S first, then prefetch K, then finish ----
        if (doA) {
          f32x16 s = {0,0,0,0,0,0,0,0,0,0,0,0,0,0,0,0};
          #pragma unroll
          for (int st = 0; st < 4; ++st)
            s = __builtin_amdgcn_mfma_f32_32x32x16_bf16(kf[st], qfA[st], s, 0, 0, 0);
          // prefetch next K (kf dead now)
          {
            const u16* kp = Kf + (size_t)tn * 2048 + lofs;
            #pragma unroll
            for (int st = 0; st < 4; ++st) kf[st] = *(const bf16x8*)(kp + st * 512);
          }
          float p[16];
          if (t == g0) {
            #pragma unroll
            for (int cr = 0; cr < 16; ++cr) {
              const int kl = ((cr & 3) + 8 * (cr >> 2)) + 4 * hi;
              p[cr] = (kl > ql) ? 0.f : fexp2(s[cr]);
            }
          } else {
            #pragma unroll
            for (int cr = 0; cr < 16; ++cr) p[cr] = fexp2(s[cr]);
          }
          #pragma unroll
          for (int cr = 0; cr < 16; ++cr) lA[cr & 3] += p[cr];
          #pragma unroll
          for (int ks = 0; ks < 2; ++ks) {
            uint4 pw;
            pw.x = cvtpk(p[ks * 8 + 0], p[ks * 8 + 1]);
            pw.y = cvtpk(p[ks * 8 + 2], p[ks * 8 + 3]);
            pw.z = cvtpk(p[ks * 8 + 4], p[ks * 8 + 5]);
            pw.w = cvtpk(p[ks * 8 + 6], p[ks * 8 + 7]);
            union { uint4 u; bf16x8 v; } pa; pa.u = pw;
            cA0 = __builtin_amdgcn_mfma_f32_32x32x16_bf16(vf[ks * 2 + 0], pa.v, cA0, 0, 0, 0);
            cA1 = __builtin_amdgcn_mfma_f32_32x32x16_bf16(vf[ks * 2 + 1], pa.v, cA1, 0, 0, 0);
          }
        } else {
          // last tile (t == g1 > g0): still prefetch (clamped harmless reload)
          const u16* kp = Kf + (size_t)tn * 2048 + lofs;
          #pragma unroll
          for (int st = 0; st < 4; ++st) kf[st] = *(const bf16x8*)(kp + st * 512);
        }

        // prefetch next V (vf dead after both PVs)
        {
          const u16* vp = Vf + (size_t)tn * 2048 + lofs;
          #pragma unroll
          for (int f = 0; f < 4; ++f) vf[f] = *(const bf16x8*)(vp + f * 512);
        }
      }
    }

    // ---- 4-way split-k merge per subtile (fixed max -> pure addition) ----
    {
      const float llA = (lA[0] + lA[1]) + (lA[2] + lA[3]);
      const float lwA = llA + swap32f(llA);
      const float llB = (lB[0] + lB[1]) + (lB[2] + lB[3]);
      const float lwB = llB + swap32f(llB);
      #pragma unroll
      for (int grp = 0; grp < 4; ++grp) {
        const int ch = grp * 2 + hi;
        f32x4 a0 = {cA0[grp * 4 + 0], cA0[grp * 4 + 1], cA0[grp * 4 + 2], cA0[grp * 4 + 3]};
        f32x4 a1 = {cA1[grp * 4 + 0], cA1[grp * 4 + 1], cA1[grp * 4 + 2], cA1[grp * 4 + 3]};
        f32x4 b0 = {cB0[grp * 4 + 0], cB0[grp * 4 + 1], cB0[grp * 4 + 2], cB0[grp * 4 + 3]};
        f32x4 b1 = {cB1[grp * 4 + 0], cB1[grp * 4 + 1], cB1[grp * 4 + 2], cB1[grp * 4 + 3]};
        *(f32x4*)&mbuf[kw][0][ql][(ch ^ ql) * 4 & 63]       = a0;
        *(f32x4*)&mbuf[kw][0][ql][((ch + 8) ^ ql) * 4 & 63] = a1;
        *(f32x4*)&mbuf[kw][1][ql][(ch ^ ql) * 4 & 63]       = b0;
        *(f32x4*)&mbuf[kw][1][ql][((ch + 8) ^ ql) * 4 & 63] = b1;
      }
      if (lane < 32) {
        lbuf[kw][0][ql] = lwA;
        lbuf[kw][1][ql] = lwB;
      }
    }
    __syncthreads();

    // each wave sums d-slice [kw*16 + hi*8, +8) over the 4 partials, per subtile
    #pragma unroll
    for (int sub = 0; sub < 2; ++sub) {
      const int qt = sub ? g1 : g0;
      const int ch0 = kw * 4 + hi * 2;
      f32x4 a0 = {0.f, 0.f, 0.f, 0.f}, a1 = {0.f, 0.f, 0.f, 0.f};
      #pragma unroll
      for (int p2 = 0; p2 < 4; ++p2) {
        a0 += *(const f32x4*)&mbuf[p2][sub][ql][(ch0 ^ ql) * 4 & 63];
        a1 += *(const f32x4*)&mbuf[p2][sub][ql][((ch0 + 1) ^ ql) * 4 & 63];
      }
      const float lt = (lbuf[0][sub][ql] + lbuf[1][sub][ql]) +
                       (lbuf[2][sub][ql] + lbuf[3][sub][ql]);
      const float inv = __builtin_amdgcn_rcpf(lt);
      uint4 pw;
      pw.x = cvtpk(a0[0] * inv, a0[1] * inv);
      pw.y = cvtpk(a0[2] * inv, a0[3] * inv);
      pw.z = cvtpk(a1[0] * inv, a1[1] * inv);
      pw.w = cvtpk(a1[2] * inv, a1[3] * inv);
      *(uint4*)(Ctx + (size_t)(b * SEQ + qt * 32 + ql) * 1024 + h * 64 + kw * 16 + hi * 8) = pw;
    }
    __syncthreads();  // protect mbuf/lbuf reuse in next pass
  }
}

// ---------------- 4) output projection + bias (fp32 out; r10, unchanged) ----------------
__device__ __forceinline__ void out_compute(
    const u16* __restrict__ AsB, const u16* __restrict__ BsB,
    int wr, int wc, int g, int lm, f32x4 acc[4][4]) {
  #pragma unroll
  for (int kk = 0; kk < 2; ++kk) {
    const int slot = ((kk * 4 + g) ^ (lm & 7)) << 3;
    bf16x8 af[4], bf[4];
    #pragma unroll
    for (int i = 0; i < 4; ++i)
      af[i] = *(const bf16x8*)(AsB + (wr * 64 + i * 16 + lm) * 64 + slot);
    #pragma unroll
    for (int n = 0; n < 4; ++n)
      bf[n] = *(const bf16x8*)(BsB + (wc * 64 + n * 16 + lm) * 64 + slot);
    #pragma unroll
    for (int i = 0; i < 4; ++i)
      #pragma unroll
      for (int n = 0; n < 4; ++n)
        acc[i][n] = __builtin_amdgcn_mfma_f32_16x16x32_bf16(af[i], bf[n], acc[i][n], 0, 0, 0);
  }
}

__global__ __launch_bounds__(256)
void gemm_out_kernel(const u16* __restrict__ Ctx, const u16* __restrict__ WoT,
                     const float* __restrict__ bo, float* __restrict__ out) {
  __shared__ u16 As[2][128 * 64];  // 32 KB
  __shared__ u16 Bs[2][128 * 64];  // 32 KB
  const int tid = threadIdx.x;
  const int lane = tid & 63;
  const int w = tid >> 6;
  const int bm = blockIdx.x * 128;
  const int bn = blockIdx.y * 128;
  const int wr = w >> 1, wc = w & 1;
  const int g = lane >> 4, lm = lane & 15;

  const int r_in = lane >> 3;
  const int s_w = lane & 7;
  const int swz_col = (s_w ^ r_in) << 3;

  const int c0 = w * 4;
  const u16* a_src = Ctx + (size_t)(bm + c0 * 8 + r_in) * D_IN + swz_col;
  const u16* b_src = WoT + (size_t)(bn + c0 * 8 + r_in) * D_IN + swz_col;

#define OUT_STAGE(BUF, K0)                                              \
  do {                                                                  \
    _Pragma("unroll")                                                   \
    for (int j = 0; j < 4; ++j) {                                       \
      GLD_LDS16(a_src + j * 8 * D_IN + (K0), &As[BUF][(c0 + j) * 512]); \
      GLD_LDS16(b_src + j * 8 * D_IN + (K0), &Bs[BUF][(c0 + j) * 512]); \
    }                                                                   \
  } while (0)

  f32x4 acc[4][4];
  #pragma unroll
  for (int i = 0; i < 4; ++i)
    #pragma unroll
    for (int n = 0; n < 4; ++n) acc[i][n] = {0.f, 0.f, 0.f, 0.f};

  OUT_STAGE(0, 0);
  OUT_STAGE(1, 64);
  #pragma unroll 1
  for (int tt = 0; tt < 7; ++tt) {
    asm volatile("s_waitcnt vmcnt(8)" ::: "memory");
    __builtin_amdgcn_s_barrier();
    out_compute(As[0], Bs[0], wr, wc, g, lm, acc);
    __builtin_amdgcn_s_barrier();
    OUT_STAGE(0, (2 * tt + 2) * 64);
    asm volatile("s_waitcnt vmcnt(8)" ::: "memory");
    __builtin_amdgcn_s_barrier();
    out_compute(As[1], Bs[1], wr, wc, g, lm, acc);
    __builtin_amdgcn_s_barrier();
    OUT_STAGE(1, (2 * tt + 3) * 64);
  }
  asm volatile("s_waitcnt vmcnt(8)" ::: "memory");
  __builtin_amdgcn_s_barrier();
  out_compute(As[0], Bs[0], wr, wc, g, lm, acc);  // t=14
  asm volatile("s_waitcnt vmcnt(0)" ::: "memory");
  __builtin_amdgcn_s_barrier();
  out_compute(As[1], Bs[1], wr, wc, g, lm, acc);  // t=15
#undef OUT_STAGE

  #pragma unroll
  for (int i = 0; i < 4; ++i)
    #pragma unroll
    for (int n = 0; n < 4; ++n)
      #pragma unroll
      for (int r = 0; r < 4; ++r) {
        const int m = bm + wr * 64 + i * 16 + g * 4 + r;
        const int cidx = bn + wc * 64 + n * 16 + lm;
        out[(size_t)m * 1024 + cidx] = acc[i][n][r] + bo[cidx];
      }
}

extern "C" void kernel_launch(void* const* d_in, const int* in_sizes, int n_in,
                              void* d_out, int out_size, void* d_ws, size_t ws_size,
                              hipStream_t stream) {
  (void)in_sizes; (void)n_in; (void)out_size; (void)ws_size;
  const float* x  = (const float*)d_in[0];
  const float* Wq = (const float*)d_in[1];
  const float* Wk = (const float*)d_in[2];
  const float* Wv = (const float*)d_in[3];
  const float* Wo = (const float*)d_in[4];
  const float* bo = (const float*)d_in[5];
  float* out = (float*)d_out;

  char* ws = (char*)d_ws;
  u16* xb  = (u16*)(ws);
  u16* WqT = (u16*)(ws + (8u << 20));
  u16* WkT = (u16*)(ws + (10u << 20));
  u16* WvT = (u16*)(ws + (12u << 20));
  u16* WoT = (u16*)(ws + (14u << 20));
  u16* Qb  = (u16*)(ws + (16u << 20));
  u16* Kb  = (u16*)(ws + (24u << 20));
  u16* Vt  = (u16*)(ws + (32u << 20));
  u16* Ctx = xb;  // xb fully consumed by gemm_qkv before attn writes Ctx

  prep_kernel<<<dim3(8192), 256, 0, stream>>>(x, xb, Wq, Wk, Wv, Wo, WqT, WkT, WvT, WoT);
  gemm_qkv_kernel<<<dim3(32, 8), 512, 0, stream>>>(xb, WqT, WkT, WvT, Qb, Kb, Vt);
  attn5_kernel<<<dim3(512), 256, 0, stream>>>(Qb, Kb, Vt, Ctx);
  gemm_out_kernel<<<dim3(32, 8), 256, 0, stream>>>(Ctx, WoT, bo, out);
}

// Round 12
// 93.129 us; speedup vs baseline: 1.0263x; 1.0263x over previous
//
#include <hip/hip_runtime.h>
#include <stdint.h>

typedef unsigned short u16;
typedef __attribute__((ext_vector_type(8))) __bf16 bf16x8;
typedef __attribute__((ext_vector_type(4))) float f32x4;
typedef __attribute__((ext_vector_type(16))) float f32x16;

#define D_IN 1024
#define NH 16
#define DH 64
#define BATCH 2
#define SEQ 2048

// log2(e)/sqrt(64): folded into Q at the QKV-projection epilogue so the
// attention kernel can use v_exp_f32 (2^x) directly with NO per-score scaling.
#define QSCL 0.1803368801111244f

#define GLD_LDS16(gp, lp)                                                              \
  __builtin_amdgcn_global_load_lds((__attribute__((address_space(1))) const void*)(gp), \
                                   (__attribute__((address_space(3))) void*)(lp), 16, 0, 0)

__device__ __forceinline__ u16 f2b(float f) {
  union { float ff; uint32_t u; } v; v.ff = f;
  return (u16)((v.u + 0x7fffu + ((v.u >> 16) & 1u)) >> 16);
}

__device__ __forceinline__ float swap32f(float v) { return __shfl_xor(v, 32, 64); }

__device__ __forceinline__ uint32_t cvtpk(float a, float b) {
  uint32_t r;
  asm("v_cvt_pk_bf16_f32 %0, %1, %2" : "=v"(r) : "v"(a), "v"(b));
  return r;
}
__device__ __forceinline__ float fexp2(float x) {
  float r;
  asm("v_exp_f32 %0, %1" : "=v"(r) : "v"(x));
  return r;
}

// ---------------- 1) fused prep: x->bf16  +  W->W^T bf16 ----------------
__global__ __launch_bounds__(256)
void prep_kernel(const float* __restrict__ x, u16* __restrict__ xb,
                 const float* __restrict__ W0, const float* __restrict__ W1,
                 const float* __restrict__ W2, const float* __restrict__ W3,
                 u16* __restrict__ T0, u16* __restrict__ T1,
                 u16* __restrict__ T2, u16* __restrict__ T3) {
  __shared__ float tile[32][33];
  if (blockIdx.x < 4096) {
    const int i = (blockIdx.x * 256 + threadIdx.x) * 4;
    const float4 v = *(const float4*)(x + i);
    uint2 pack;
    pack.x = (uint32_t)f2b(v.x) | ((uint32_t)f2b(v.y) << 16);
    pack.y = (uint32_t)f2b(v.z) | ((uint32_t)f2b(v.w) << 16);
    *(uint2*)(xb + i) = pack;
  } else {
    const int bid2 = blockIdx.x - 4096;
    const float* W; u16* T;
    switch (bid2 >> 10) {
      case 0: W = W0; T = T0; break;
      case 1: W = W1; T = T1; break;
      case 2: W = W2; T = T2; break;
      default: W = W3; T = T3; break;
    }
    const int rem = bid2 & 1023;
    const int n0 = (rem >> 5) * 32, k0 = (rem & 31) * 32;
    const int tx = threadIdx.x & 31, ty = threadIdx.x >> 5;
    #pragma unroll
    for (int i = 0; i < 32; i += 8)
      tile[ty + i][tx] = W[(size_t)(k0 + ty + i) * D_IN + n0 + tx];
    __syncthreads();
    #pragma unroll
    for (int i = 0; i < 32; i += 8)
      T[(size_t)(n0 + ty + i) * D_IN + k0 + tx] = f2b(tile[tx][ty + i]);
  }
}

// ---------------- 2) FUSED QKV projection GEMM (r10, unchanged) ----------------
__device__ __forceinline__ void qkv_compute(
    const u16* __restrict__ AsB, const u16* __restrict__ Bq,
    const u16* __restrict__ Bk, const u16* __restrict__ Bv,
    int wm, int wn, int g, int lm,
    f32x4 accq[4][2], f32x4 acck[4][2], f32x4 accv[4][2]) {
  #pragma unroll
  for (int kk = 0; kk < 2; ++kk) {
    const int slot = ((kk * 4 + g) ^ (lm & 7)) << 3;
    bf16x8 af[4];
    #pragma unroll
    for (int i = 0; i < 4; ++i)
      af[i] = *(const bf16x8*)(AsB + (wm * 64 + i * 16 + lm) * 64 + slot);
    bf16x8 bq[2], bk[2], bv[2];
    #pragma unroll
    for (int n = 0; n < 2; ++n) {
      const int ro = (wn * 32 + n * 16 + lm) * 64 + slot;
      bq[n] = *(const bf16x8*)(Bq + ro);
      bk[n] = *(const bf16x8*)(Bk + ro);
      bv[n] = *(const bf16x8*)(Bv + ro);
    }
    #pragma unroll
    for (int i = 0; i < 4; ++i)
      #pragma unroll
      for (int n = 0; n < 2; ++n) {
        accq[i][n] = __builtin_amdgcn_mfma_f32_16x16x32_bf16(af[i], bq[n], accq[i][n], 0, 0, 0);
        acck[i][n] = __builtin_amdgcn_mfma_f32_16x16x32_bf16(af[i], bk[n], acck[i][n], 0, 0, 0);
        accv[i][n] = __builtin_amdgcn_mfma_f32_16x16x32_bf16(af[i], bv[n], accv[i][n], 0, 0, 0);
      }
  }
}

__global__ __launch_bounds__(512)
void gemm_qkv_kernel(const u16* __restrict__ Xb,
                     const u16* __restrict__ WqT, const u16* __restrict__ WkT,
                     const u16* __restrict__ WvT,
                     u16* __restrict__ Qo, u16* __restrict__ Ko, u16* __restrict__ Vt) {
  __shared__ u16 As[2][128 * 64];     // 32 KB
  __shared__ u16 Bs[2][3][128 * 64];  // 96 KB

  const int tid = threadIdx.x;
  const int lane = tid & 63;
  const int w = tid >> 6;            // 0..7
  const int wm = w >> 2, wn = w & 3; // wave tile 64x32 per which
  const int bm = blockIdx.x * 128;
  const int bn = blockIdx.y * 128;
  const int g = lane >> 4, lm = lane & 15;

  const int r_in = lane >> 3;
  const int s_w = lane & 7;
  const int swz_col = (s_w ^ r_in) << 3;

  const int c0 = w * 2;  // this wave's chunk base (2 chunks of 8 rows each)
  const u16* a_src0 = Xb + (size_t)(bm + c0 * 8 + r_in) * D_IN + swz_col;
  const u16* a_src1 = a_src0 + 8 * D_IN;
  const u16* q_src0 = WqT + (size_t)(bn + c0 * 8 + r_in) * D_IN + swz_col;
  const u16* q_src1 = q_src0 + 8 * D_IN;
  const u16* k_src0 = WkT + (size_t)(bn + c0 * 8 + r_in) * D_IN + swz_col;
  const u16* k_src1 = k_src0 + 8 * D_IN;
  const u16* v_src0 = WvT + (size_t)(bn + c0 * 8 + r_in) * D_IN + swz_col;
  const u16* v_src1 = v_src0 + 8 * D_IN;

#define QKV_STAGE(BUF, K0)                                 \
  do {                                                     \
    GLD_LDS16(a_src0 + (K0), &As[BUF][c0 * 512]);          \
    GLD_LDS16(a_src1 + (K0), &As[BUF][c0 * 512 + 512]);    \
    GLD_LDS16(q_src0 + (K0), &Bs[BUF][0][c0 * 512]);       \
    GLD_LDS16(q_src1 + (K0), &Bs[BUF][0][c0 * 512 + 512]); \
    GLD_LDS16(k_src0 + (K0), &Bs[BUF][1][c0 * 512]);       \
    GLD_LDS16(k_src1 + (K0), &Bs[BUF][1][c0 * 512 + 512]); \
    GLD_LDS16(v_src0 + (K0), &Bs[BUF][2][c0 * 512]);       \
    GLD_LDS16(v_src1 + (K0), &Bs[BUF][2][c0 * 512 + 512]); \
  } while (0)

  f32x4 accq[4][2], acck[4][2], accv[4][2];
  #pragma unroll
  for (int i = 0; i < 4; ++i)
    #pragma unroll
    for (int n = 0; n < 2; ++n) {
      accq[i][n] = {0.f, 0.f, 0.f, 0.f};
      acck[i][n] = {0.f, 0.f, 0.f, 0.f};
      accv[i][n] = {0.f, 0.f, 0.f, 0.f};
    }

  QKV_STAGE(0, 0);
  QKV_STAGE(1, 64);
  #pragma unroll 1
  for (int tt = 0; tt < 7; ++tt) {
    asm volatile("s_waitcnt vmcnt(8)" ::: "memory");
    __builtin_amdgcn_s_barrier();
    qkv_compute(As[0], Bs[0][0], Bs[0][1], Bs[0][2], wm, wn, g, lm, accq, acck, accv);
    __builtin_amdgcn_s_barrier();
    QKV_STAGE(0, (2 * tt + 2) * 64);
    asm volatile("s_waitcnt vmcnt(8)" ::: "memory");
    __builtin_amdgcn_s_barrier();
    qkv_compute(As[1], Bs[1][0], Bs[1][1], Bs[1][2], wm, wn, g, lm, accq, acck, accv);
    __builtin_amdgcn_s_barrier();
    QKV_STAGE(1, (2 * tt + 3) * 64);
  }
  asm volatile("s_waitcnt vmcnt(8)" ::: "memory");
  __builtin_amdgcn_s_barrier();
  qkv_compute(As[0], Bs[0][0], Bs[0][1], Bs[0][2], wm, wn, g, lm, accq, acck, accv);  // t=14
  asm volatile("s_waitcnt vmcnt(0)" ::: "memory");
  __builtin_amdgcn_s_barrier();
  qkv_compute(As[1], Bs[1][0], Bs[1][1], Bs[1][2], wm, wn, g, lm, accq, acck, accv);  // t=15
#undef QKV_STAGE

  // epilogue: scatter Q (scaled), K, V(fragment-permuted) -- r6-verified index math
  #pragma unroll
  for (int i = 0; i < 4; ++i) {
    #pragma unroll
    for (int n = 0; n < 2; ++n) {
      #pragma unroll
      for (int r = 0; r < 4; ++r) {
        const int m = bm + wm * 64 + i * 16 + g * 4 + r;
        const int c = bn + wn * 32 + n * 16 + lm;
        const int b = m >> 11, nn = m & (SEQ - 1);
        const int h = c >> 6, d = c & (DH - 1);
        const int bh = b * NH + h;
        const int t = nn >> 5;
        {
          const u16 val = f2b(accq[i][n][r] * QSCL);
          const int st = d >> 4;
          const int lane2 = ((d >> 3) & 1) * 32 + (nn & 31);
          const int j = d & 7;
          Qo[((size_t)(bh * 64 + t) * 4 + st) * 512 + lane2 * 8 + j] = val;
        }
        {
          const u16 val = f2b(acck[i][n][r]);
          const int st = d >> 4;
          const int lane2 = ((d >> 3) & 1) * 32 + (nn & 31);
          const int j = d & 7;
          Ko[((size_t)(bh * 64 + t) * 4 + st) * 512 + lane2 * 8 + j] = val;
        }
        {
          const u16 val = f2b(accv[i][n][r]);
          const int n5 = nn & 31;
          const int f = (n5 >> 4) * 2 + (d >> 5);
          const int lane2 = ((n5 >> 2) & 1) * 32 + (d & 31);
          const int j = ((n5 >> 3) & 1) * 4 + (n5 & 3);
          Vt[((size_t)(bh * 64 + t) * 4 + f) * 512 + lane2 * 8 + j] = val;
        }
      }
    }
  }
}

// ---------------- 3) causal flash attention: fixed-max, 4-way split-k (r10 attn4) ----------------
// REVERTED from r11's paired-subtile attn5: halving K/V traffic made attn 2x
// SLOWER (41us vs ~22) -> attn is latency/ILP-bound, NOT L2-BW-bound. r10
// structure restored: 1024 blocks x 4 waves, one q-subtile per wave-step,
// shortest per-tile dependency chain, max wave parallelism.
// NEW (T5, m191 regime: free-running waves, no main-loop barrier): setprio(1)
// around the MFMA clusters so MFMA-entering waves win CU issue arbitration.
__global__ __launch_bounds__(256)
void attn4_kernel(const u16* __restrict__ Qb, const u16* __restrict__ Kb,
                  const u16* __restrict__ Vt, u16* __restrict__ Ctx) {
  __shared__ float mbuf[4][32][64];   // [wave][q][d], chunk-XOR-swizzled
  __shared__ float lbuf[4][32];

  const int tid = threadIdx.x;
  const int lane = tid & 63;
  const int kw = tid >> 6;             // wave = split-k slot 0..3
  const int ql = lane & 31;
  const int hi = lane >> 5;
  const int bid = blockIdx.x;
  const int c = bid & 7;
  const int r = bid >> 3;              // 0..127
  const int jj = r & 31;               // pair index
  const int bh = c + 8 * (r >> 5);     // 0..31
  const int b = bh >> 4, h = bh & 15;

  const u16* Qf = Qb + (size_t)bh * 64 * 2048;
  const u16* Kf = Kb + (size_t)bh * 64 * 2048;
  const u16* Vf = Vt + (size_t)bh * 64 * 2048;
  const int lofs = lane * 8;

  #pragma unroll 1
  for (int pass = 0; pass < 2; ++pass) {
    const int qt = pass ? (63 - jj) : jj;
    const int qb0 = qt * 32;

    bf16x8 qf[4];
    {
      const u16* qp = Qf + (size_t)qt * 2048 + lofs;
      #pragma unroll
      for (int st = 0; st < 4; ++st) qf[st] = *(const bf16x8*)(qp + st * 512);
    }

    f32x16 ctx0 = {0,0,0,0,0,0,0,0,0,0,0,0,0,0,0,0};
    f32x16 ctx1 = {0,0,0,0,0,0,0,0,0,0,0,0,0,0,0,0};
    float lacc[4] = {0.f, 0.f, 0.f, 0.f};

    bf16x8 kf[4], vf[4];
    if (kw <= qt) {
      // prologue load: tile kw
      {
        const u16* kp = Kf + (size_t)kw * 2048 + lofs;
        const u16* vp = Vf + (size_t)kw * 2048 + lofs;
        #pragma unroll
        for (int st = 0; st < 4; ++st) kf[st] = *(const bf16x8*)(kp + st * 512);
        #pragma unroll
        for (int f = 0; f < 4; ++f) vf[f] = *(const bf16x8*)(vp + f * 512);
      }
      #pragma unroll 2
      for (int t = kw; t <= qt; t += 4) {
        // ---- QK^T (S^T: key-in-reg, q-in-lane) ----
        f32x16 s = {0,0,0,0,0,0,0,0,0,0,0,0,0,0,0,0};
        __builtin_amdgcn_s_setprio(1);
        #pragma unroll
        for (int st = 0; st < 4; ++st)
          s = __builtin_amdgcn_mfma_f32_32x32x16_bf16(kf[st], qf[st], s, 0, 0, 0);
        __builtin_amdgcn_s_setprio(0);

        // prefetch next tile's K (kf dead after QK); clamped reload on last iter
        const int tn = (t + 4 <= qt) ? (t + 4) : qt;
        {
          const u16* kp = Kf + (size_t)tn * 2048 + lofs;
          #pragma unroll
          for (int st = 0; st < 4; ++st) kf[st] = *(const bf16x8*)(kp + st * 512);
        }

        // ---- softmax (fixed max = 0) ----
        float p[16];
        if (t == qt) {  // diagonal tile: causal mask (wave-uniform branch)
          #pragma unroll
          for (int cr = 0; cr < 16; ++cr) {
            const int kl = ((cr & 3) + 8 * (cr >> 2)) + 4 * hi;
            p[cr] = (kl > ql) ? 0.f : fexp2(s[cr]);
          }
        } else {
          #pragma unroll
          for (int cr = 0; cr < 16; ++cr) p[cr] = fexp2(s[cr]);
        }
        #pragma unroll
        for (int cr = 0; cr < 16; ++cr) lacc[cr & 3] += p[cr];

        // ---- PV: fragment k-order baked into V's stored layout ----
        __builtin_amdgcn_s_setprio(1);
        #pragma unroll
        for (int ks = 0; ks < 2; ++ks) {
          uint4 pw;
          pw.x = cvtpk(p[ks * 8 + 0], p[ks * 8 + 1]);
          pw.y = cvtpk(p[ks * 8 + 2], p[ks * 8 + 3]);
          pw.z = cvtpk(p[ks * 8 + 4], p[ks * 8 + 5]);
          pw.w = cvtpk(p[ks * 8 + 6], p[ks * 8 + 7]);
          union { uint4 u; bf16x8 v; } pa; pa.u = pw;
          ctx0 = __builtin_amdgcn_mfma_f32_32x32x16_bf16(vf[ks * 2 + 0], pa.v, ctx0, 0, 0, 0);
          ctx1 = __builtin_amdgcn_mfma_f32_32x32x16_bf16(vf[ks * 2 + 1], pa.v, ctx1, 0, 0, 0);
        }
        __builtin_amdgcn_s_setprio(0);

        // prefetch next tile's V (vf dead after PV)
        {
          const u16* vp = Vf + (size_t)tn * 2048 + lofs;
          #pragma unroll
          for (int f = 0; f < 4; ++f) vf[f] = *(const bf16x8*)(vp + f * 512);
        }
      }
    }

    // ---- 4-way split-k merge (fixed max -> pure addition) ----
    const float lloc = (lacc[0] + lacc[1]) + (lacc[2] + lacc[3]);
    const float lwv = lloc + swap32f(lloc);

    // write partial ctx: chunk ch = d/4, stored at ch ^ (q&15) (bank-conflict-free)
    #pragma unroll
    for (int grp = 0; grp < 4; ++grp) {
      const int ch = grp * 2 + hi;
      f32x4 t0 = {ctx0[grp * 4 + 0], ctx0[grp * 4 + 1], ctx0[grp * 4 + 2], ctx0[grp * 4 + 3]};
      f32x4 t1 = {ctx1[grp * 4 + 0], ctx1[grp * 4 + 1], ctx1[grp * 4 + 2], ctx1[grp * 4 + 3]};
      *(f32x4*)&mbuf[kw][ql][(ch ^ ql) * 4 & 63]       = t0;
      *(f32x4*)&mbuf[kw][ql][((ch + 8) ^ ql) * 4 & 63] = t1;
    }
    if (lane < 32) lbuf[kw][ql] = lwv;
    __syncthreads();

    // each wave sums d-slice [kw*16 + hi*8, +8) over the 4 partials
    {
      const int ch0 = kw * 4 + hi * 2;
      f32x4 a0 = {0.f, 0.f, 0.f, 0.f}, a1 = {0.f, 0.f, 0.f, 0.f};
      #pragma unroll
      for (int p2 = 0; p2 < 4; ++p2) {
        a0 += *(const f32x4*)&mbuf[p2][ql][(ch0 ^ ql) * 4 & 63];
        a1 += *(const f32x4*)&mbuf[p2][ql][((ch0 + 1) ^ ql) * 4 & 63];
      }
      const float lt = (lbuf[0][ql] + lbuf[1][ql]) + (lbuf[2][ql] + lbuf[3][ql]);
      const float inv = __builtin_amdgcn_rcpf(lt);
      uint4 pw;
      pw.x = cvtpk(a0[0] * inv, a0[1] * inv);
      pw.y = cvtpk(a0[2] * inv, a0[3] * inv);
      pw.z = cvtpk(a1[0] * inv, a1[1] * inv);
      pw.w = cvtpk(a1[2] * inv, a1[3] * inv);
      *(uint4*)(Ctx + (size_t)(b * SEQ + qb0 + ql) * 1024 + h * 64 + kw * 16 + hi * 8) = pw;
    }
    __syncthreads();  // protect mbuf/lbuf reuse in next pass
  }
}

// ---------------- 4) output projection + bias (fp32 out; r10, unchanged) ----------------
__device__ __forceinline__ void out_compute(
    const u16* __restrict__ AsB, const u16* __restrict__ BsB,
    int wr, int wc, int g, int lm, f32x4 acc[4][4]) {
  #pragma unroll
  for (int kk = 0; kk < 2; ++kk) {
    const int slot = ((kk * 4 + g) ^ (lm & 7)) << 3;
    bf16x8 af[4], bf[4];
    #pragma unroll
    for (int i = 0; i < 4; ++i)
      af[i] = *(const bf16x8*)(AsB + (wr * 64 + i * 16 + lm) * 64 + slot);
    #pragma unroll
    for (int n = 0; n < 4; ++n)
      bf[n] = *(const bf16x8*)(BsB + (wc * 64 + n * 16 + lm) * 64 + slot);
    #pragma unroll
    for (int i = 0; i < 4; ++i)
      #pragma unroll
      for (int n = 0; n < 4; ++n)
        acc[i][n] = __builtin_amdgcn_mfma_f32_16x16x32_bf16(af[i], bf[n], acc[i][n], 0, 0, 0);
  }
}

__global__ __launch_bounds__(256)
void gemm_out_kernel(const u16* __restrict__ Ctx, const u16* __restrict__ WoT,
                     const float* __restrict__ bo, float* __restrict__ out) {
  __shared__ u16 As[2][128 * 64];  // 32 KB
  __shared__ u16 Bs[2][128 * 64];  // 32 KB
  const int tid = threadIdx.x;
  const int lane = tid & 63;
  const int w = tid >> 6;
  const int bm = blockIdx.x * 128;
  const int bn = blockIdx.y * 128;
  const int wr = w >> 1, wc = w & 1;
  const int g = lane >> 4, lm = lane & 15;

  const int r_in = lane >> 3;
  const int s_w = lane & 7;
  const int swz_col = (s_w ^ r_in) << 3;

  const int c0 = w * 4;
  const u16* a_src = Ctx + (size_t)(bm + c0 * 8 + r_in) * D_IN + swz_col;
  const u16* b_src = WoT + (size_t)(bn + c0 * 8 + r_in) * D_IN + swz_col;

#define OUT_STAGE(BUF, K0)                                              \
  do {                                                                  \
    _Pragma("unroll")                                                   \
    for (int j = 0; j < 4; ++j) {                                       \
      GLD_LDS16(a_src + j * 8 * D_IN + (K0), &As[BUF][(c0 + j) * 512]); \
      GLD_LDS16(b_src + j * 8 * D_IN + (K0), &Bs[BUF][(c0 + j) * 512]); \
    }                                                                   \
  } while (0)

  f32x4 acc[4][4];
  #pragma unroll
  for (int i = 0; i < 4; ++i)
    #pragma unroll
    for (int n = 0; n < 4; ++n) acc[i][n] = {0.f, 0.f, 0.f, 0.f};

  OUT_STAGE(0, 0);
  OUT_STAGE(1, 64);
  #pragma unroll 1
  for (int tt = 0; tt < 7; ++tt) {
    asm volatile("s_waitcnt vmcnt(8)" ::: "memory");
    __builtin_amdgcn_s_barrier();
    out_compute(As[0], Bs[0], wr, wc, g, lm, acc);
    __builtin_amdgcn_s_barrier();
    OUT_STAGE(0, (2 * tt + 2) * 64);
    asm volatile("s_waitcnt vmcnt(8)" ::: "memory");
    __builtin_amdgcn_s_barrier();
    out_compute(As[1], Bs[1], wr, wc, g, lm, acc);
    __builtin_amdgcn_s_barrier();
    OUT_STAGE(1, (2 * tt + 3) * 64);
  }
  asm volatile("s_waitcnt vmcnt(8)" ::: "memory");
  __builtin_amdgcn_s_barrier();
  out_compute(As[0], Bs[0], wr, wc, g, lm, acc);  // t=14
  asm volatile("s_waitcnt vmcnt(0)" ::: "memory");
  __builtin_amdgcn_s_barrier();
  out_compute(As[1], Bs[1], wr, wc, g, lm, acc);  // t=15
#undef OUT_STAGE

  #pragma unroll
  for (int i = 0; i < 4; ++i)
    #pragma unroll
    for (int n = 0; n < 4; ++n)
      #pragma unroll
      for (int r = 0; r < 4; ++r) {
        const int m = bm + wr * 64 + i * 16 + g * 4 + r;
        const int cidx = bn + wc * 64 + n * 16 + lm;
        out[(size_t)m * 1024 + cidx] = acc[i][n][r] + bo[cidx];
      }
}

extern "C" void kernel_launch(void* const* d_in, const int* in_sizes, int n_in,
                              void* d_out, int out_size, void* d_ws, size_t ws_size,
                              hipStream_t stream) {
  (void)in_sizes; (void)n_in; (void)out_size; (void)ws_size;
  const float* x  = (const float*)d_in[0];
  const float* Wq = (const float*)d_in[1];
  const float* Wk = (const float*)d_in[2];
  const float* Wv = (const float*)d_in[3];
  const float* Wo = (const float*)d_in[4];
  const float* bo = (const float*)d_in[5];
  float* out = (float*)d_out;

  char* ws = (char*)d_ws;
  u16* xb  = (u16*)(ws);
  u16* WqT = (u16*)(ws + (8u << 20));
  u16* WkT = (u16*)(ws + (10u << 20));
  u16* WvT = (u16*)(ws + (12u << 20));
  u16* WoT = (u16*)(ws + (14u << 20));
  u16* Qb  = (u16*)(ws + (16u << 20));
  u16* Kb  = (u16*)(ws + (24u << 20));
  u16* Vt  = (u16*)(ws + (32u << 20));
  u16* Ctx = xb;  // xb fully consumed by gemm_qkv before attn writes Ctx

  prep_kernel<<<dim3(8192), 256, 0, stream>>>(x, xb, Wq, Wk, Wv, Wo, WqT, WkT, WvT, WoT);
  gemm_qkv_kernel<<<dim3(32, 8), 512, 0, stream>>>(xb, WqT, WkT, WvT, Qb, Kb, Vt);
  attn4_kernel<<<dim3(1024), 256, 0, stream>>>(Qb, Kb, Vt, Ctx);
  gemm_out_kernel<<<dim3(32, 8), 256, 0, stream>>>(Ctx, WoT, bo, out);
}

// Round 14
// 88.286 us; speedup vs baseline: 1.0826x; 1.0549x over previous
//
#include <hip/hip_runtime.h>
#include <stdint.h>

typedef unsigned short u16;
typedef __attribute__((ext_vector_type(8))) __bf16 bf16x8;
typedef __attribute__((ext_vector_type(4))) float f32x4;
typedef __attribute__((ext_vector_type(16))) float f32x16;

#define D_IN 1024
#define NH 16
#define DH 64
#define BATCH 2
#define SEQ 2048

// log2(e)/sqrt(64): folded into Q at the QKV-projection epilogue so the
// attention kernel can use v_exp_f32 (2^x) directly with NO per-score scaling.
#define QSCL 0.1803368801111244f

#define GLD_LDS16(gp, lp)                                                              \
  __builtin_amdgcn_global_load_lds((__attribute__((address_space(1))) const void*)(gp), \
                                   (__attribute__((address_space(3))) void*)(lp), 16, 0, 0)

__device__ __forceinline__ u16 f2b(float f) {
  union { float ff; uint32_t u; } v; v.ff = f;
  return (u16)((v.u + 0x7fffu + ((v.u >> 16) & 1u)) >> 16);
}

__device__ __forceinline__ float swap32f(float v) { return __shfl_xor(v, 32, 64); }

__device__ __forceinline__ uint32_t cvtpk(float a, float b) {
  uint32_t r;
  asm("v_cvt_pk_bf16_f32 %0, %1, %2" : "=v"(r) : "v"(a), "v"(b));
  return r;
}
__device__ __forceinline__ float fexp2(float x) {
  float r;
  asm("v_exp_f32 %0, %1" : "=v"(r) : "v"(x));
  return r;
}

// ---------------- 1) fused prep: x->bf16  +  W->W^T bf16 ----------------
__global__ __launch_bounds__(256)
void prep_kernel(const float* __restrict__ x, u16* __restrict__ xb,
                 const float* __restrict__ W0, const float* __restrict__ W1,
                 const float* __restrict__ W2, const float* __restrict__ W3,
                 u16* __restrict__ T0, u16* __restrict__ T1,
                 u16* __restrict__ T2, u16* __restrict__ T3) {
  __shared__ float tile[32][33];
  if (blockIdx.x < 4096) {
    const int i = (blockIdx.x * 256 + threadIdx.x) * 4;
    const float4 v = *(const float4*)(x + i);
    uint2 pack;
    pack.x = (uint32_t)f2b(v.x) | ((uint32_t)f2b(v.y) << 16);
    pack.y = (uint32_t)f2b(v.z) | ((uint32_t)f2b(v.w) << 16);
    *(uint2*)(xb + i) = pack;
  } else {
    const int bid2 = blockIdx.x - 4096;
    const float* W; u16* T;
    switch (bid2 >> 10) {
      case 0: W = W0; T = T0; break;
      case 1: W = W1; T = T1; break;
      case 2: W = W2; T = T2; break;
      default: W = W3; T = T3; break;
    }
    const int rem = bid2 & 1023;
    const int n0 = (rem >> 5) * 32, k0 = (rem & 31) * 32;
    const int tx = threadIdx.x & 31, ty = threadIdx.x >> 5;
    #pragma unroll
    for (int i = 0; i < 32; i += 8)
      tile[ty + i][tx] = W[(size_t)(k0 + ty + i) * D_IN + n0 + tx];
    __syncthreads();
    #pragma unroll
    for (int i = 0; i < 32; i += 8)
      T[(size_t)(n0 + ty + i) * D_IN + k0 + tx] = f2b(tile[tx][ty + i]);
  }
}

// ---------------- 2) FUSED QKV projection GEMM ----------------
// r10 main loop (counted-vmcnt 2-buffer pipeline, 48 MFMA/wave/step) unchanged.
// Epilogue: repack the 12 output fragments (4 Q + 4 K + 4 V, 1 KB each) through
// the dead staging LDS, then store each as ONE coalesced uint4/lane.
// r13 BUG FIXED: T0v must be the WITHIN-BATCH tile index ((M0 & (SEQ-1))>>5) --
// the global (b*64+t) variant double-counted the batch already folded into bh,
// corrupting all batch-1 outputs (absmax 2.17).
__device__ __forceinline__ void qkv_compute(
    const u16* __restrict__ AsB, const u16* __restrict__ Bq,
    const u16* __restrict__ Bk, const u16* __restrict__ Bv,
    int wm, int wn, int g, int lm,
    f32x4 accq[4][2], f32x4 acck[4][2], f32x4 accv[4][2]) {
  #pragma unroll
  for (int kk = 0; kk < 2; ++kk) {
    const int slot = ((kk * 4 + g) ^ (lm & 7)) << 3;
    bf16x8 af[4];
    #pragma unroll
    for (int i = 0; i < 4; ++i)
      af[i] = *(const bf16x8*)(AsB + (wm * 64 + i * 16 + lm) * 64 + slot);
    bf16x8 bq[2], bk[2], bv[2];
    #pragma unroll
    for (int n = 0; n < 2; ++n) {
      const int ro = (wn * 32 + n * 16 + lm) * 64 + slot;
      bq[n] = *(const bf16x8*)(Bq + ro);
      bk[n] = *(const bf16x8*)(Bk + ro);
      bv[n] = *(const bf16x8*)(Bv + ro);
    }
    #pragma unroll
    for (int i = 0; i < 4; ++i)
      #pragma unroll
      for (int n = 0; n < 2; ++n) {
        accq[i][n] = __builtin_amdgcn_mfma_f32_16x16x32_bf16(af[i], bq[n], accq[i][n], 0, 0, 0);
        acck[i][n] = __builtin_amdgcn_mfma_f32_16x16x32_bf16(af[i], bk[n], acck[i][n], 0, 0, 0);
        accv[i][n] = __builtin_amdgcn_mfma_f32_16x16x32_bf16(af[i], bv[n], accv[i][n], 0, 0, 0);
      }
  }
}

__global__ __launch_bounds__(512)
void gemm_qkv_kernel(const u16* __restrict__ Xb,
                     const u16* __restrict__ WqT, const u16* __restrict__ WkT,
                     const u16* __restrict__ WvT,
                     u16* __restrict__ Qo, u16* __restrict__ Ko, u16* __restrict__ Vt) {
  __shared__ u16 smem[65536];          // 128 KB: As[2] | Bs[2][3]
  u16* As0 = smem;                     // As[buf] = As0 + buf*8192
  u16* Bs0 = smem + 16384;             // Bs[buf][wh] = Bs0 + buf*24576 + wh*8192

  const int tid = threadIdx.x;
  const int lane = tid & 63;
  const int w = tid >> 6;            // 0..7
  const int wm = w >> 2, wn = w & 3; // wave tile 64x32 per which
  const int bm = blockIdx.x * 128;
  const int bn = blockIdx.y * 128;
  const int g = lane >> 4, lm = lane & 15;

  const int r_in = lane >> 3;
  const int s_w = lane & 7;
  const int swz_col = (s_w ^ r_in) << 3;

  const int c0 = w * 2;  // this wave's chunk base (2 chunks of 8 rows each)
  const u16* a_src0 = Xb + (size_t)(bm + c0 * 8 + r_in) * D_IN + swz_col;
  const u16* a_src1 = a_src0 + 8 * D_IN;
  const u16* q_src0 = WqT + (size_t)(bn + c0 * 8 + r_in) * D_IN + swz_col;
  const u16* q_src1 = q_src0 + 8 * D_IN;
  const u16* k_src0 = WkT + (size_t)(bn + c0 * 8 + r_in) * D_IN + swz_col;
  const u16* k_src1 = k_src0 + 8 * D_IN;
  const u16* v_src0 = WvT + (size_t)(bn + c0 * 8 + r_in) * D_IN + swz_col;
  const u16* v_src1 = v_src0 + 8 * D_IN;

#define QKV_STAGE(BUF, K0)                                            \
  do {                                                                \
    GLD_LDS16(a_src0 + (K0), As0 + (BUF)*8192 + c0 * 512);            \
    GLD_LDS16(a_src1 + (K0), As0 + (BUF)*8192 + c0 * 512 + 512);      \
    GLD_LDS16(q_src0 + (K0), Bs0 + (BUF)*24576 + c0 * 512);           \
    GLD_LDS16(q_src1 + (K0), Bs0 + (BUF)*24576 + c0 * 512 + 512);     \
    GLD_LDS16(k_src0 + (K0), Bs0 + (BUF)*24576 + 8192 + c0 * 512);    \
    GLD_LDS16(k_src1 + (K0), Bs0 + (BUF)*24576 + 8192 + c0 * 512 + 512); \
    GLD_LDS16(v_src0 + (K0), Bs0 + (BUF)*24576 + 16384 + c0 * 512);   \
    GLD_LDS16(v_src1 + (K0), Bs0 + (BUF)*24576 + 16384 + c0 * 512 + 512); \
  } while (0)

  f32x4 accq[4][2], acck[4][2], accv[4][2];
  #pragma unroll
  for (int i = 0; i < 4; ++i)
    #pragma unroll
    for (int n = 0; n < 2; ++n) {
      accq[i][n] = {0.f, 0.f, 0.f, 0.f};
      acck[i][n] = {0.f, 0.f, 0.f, 0.f};
      accv[i][n] = {0.f, 0.f, 0.f, 0.f};
    }

  QKV_STAGE(0, 0);
  QKV_STAGE(1, 64);
  #pragma unroll 1
  for (int tt = 0; tt < 7; ++tt) {
    asm volatile("s_waitcnt vmcnt(8)" ::: "memory");
    __builtin_amdgcn_s_barrier();
    qkv_compute(As0, Bs0, Bs0 + 8192, Bs0 + 16384, wm, wn, g, lm, accq, acck, accv);
    __builtin_amdgcn_s_barrier();
    QKV_STAGE(0, (2 * tt + 2) * 64);
    asm volatile("s_waitcnt vmcnt(8)" ::: "memory");
    __builtin_amdgcn_s_barrier();
    qkv_compute(As0 + 8192, Bs0 + 24576, Bs0 + 32768, Bs0 + 40960, wm, wn, g, lm,
                accq, acck, accv);
    __builtin_amdgcn_s_barrier();
    QKV_STAGE(1, (2 * tt + 3) * 64);
  }
  asm volatile("s_waitcnt vmcnt(8)" ::: "memory");
  __builtin_amdgcn_s_barrier();
  qkv_compute(As0, Bs0, Bs0 + 8192, Bs0 + 16384, wm, wn, g, lm, accq, acck, accv);  // t=14
  asm volatile("s_waitcnt vmcnt(0)" ::: "memory");
  __builtin_amdgcn_s_barrier();
  qkv_compute(As0 + 8192, Bs0 + 24576, Bs0 + 32768, Bs0 + 40960, wm, wn, g, lm,
              accq, acck, accv);  // t=15
#undef QKV_STAGE

  // ---- epilogue: LDS repack -> coalesced fragment stores ----
  __syncthreads();                       // staging LDS now safely reusable
  u16* pool = smem + w * 6144;           // 12 KB per wave: Q[0,2048) K[2048,4096) V[4096,6144)
  const int M0 = bm + wm * 64;
  const int T0v = (M0 & (SEQ - 1)) >> 5; // WITHIN-BATCH tile base (r13 bug: was M0>>5)
  const int C0 = bn + wn * 32;
  const int D0 = C0 & 63;                // 0 or 32
  const int S0 = D0 >> 4;                // st base (0 or 2)
  const int d5 = D0 >> 5;                // 0 or 1
  const int bh = (M0 >> 11) * NH + (C0 >> 6);

  #pragma unroll
  for (int i = 0; i < 4; ++i) {
    const int ti = i >> 1;
    const int nbase = (i & 1) * 16 + g * 4;          // nn&31, minus r
    #pragma unroll
    for (int n = 0; n < 2; ++n) {
      #pragma unroll
      for (int r = 0; r < 4; ++r) {
        // Q/K: lane2 = ((d>>3)&1)*32 + (nn&31); j = d&7
        const int offqk = (ti * 2 + n) * 512 + (((lm >> 3) << 5) + nbase + r) * 8 + (lm & 7);
        pool[offqk] = f2b(accq[i][n][r] * QSCL);
        pool[2048 + offqk] = f2b(acck[i][n][r]);
        // V: lane2 = (g&1)*32 + (d&31); j = (g>>1)*4 + r; frag slot = ti*2 + (i&1)
        const int offv = 4096 + (ti * 2 + (i & 1)) * 512 +
                         ((g & 1) * 32 + n * 16 + lm) * 8 + ((g >> 1) << 2) + r;
        pool[offv] = f2b(accv[i][n][r]);
      }
    }
  }
  asm volatile("s_waitcnt lgkmcnt(0)" ::: "memory");
  #pragma unroll
  for (int fl = 0; fl < 4; ++fl) {
    const int t = T0v + (fl >> 1);
    const int st = S0 + (fl & 1);
    const uint4 vq = *(const uint4*)(pool + fl * 512 + lane * 8);
    *(uint4*)(Qo + ((size_t)(bh * 64 + t) * 4 + st) * 512 + lane * 8) = vq;
    const uint4 vk = *(const uint4*)(pool + 2048 + fl * 512 + lane * 8);
    *(uint4*)(Ko + ((size_t)(bh * 64 + t) * 4 + st) * 512 + lane * 8) = vk;
    const int f = ((fl & 1) << 1) + d5;
    const uint4 vv = *(const uint4*)(pool + 4096 + fl * 512 + lane * 8);
    *(uint4*)(Vt + ((size_t)(bh * 64 + t) * 4 + f) * 512 + lane * 8) = vv;
  }
}

// ---------------- 3) causal flash attention: fixed-max, 4-way split-k (r10 attn4) ----------------
// r10 form exactly. 1024 blocks x 4 waves, one q-subtile per wave, k split mod 4.
__global__ __launch_bounds__(256)
void attn4_kernel(const u16* __restrict__ Qb, const u16* __restrict__ Kb,
                  const u16* __restrict__ Vt, u16* __restrict__ Ctx) {
  __shared__ float mbuf[4][32][64];   // [wave][q][d], chunk-XOR-swizzled
  __shared__ float lbuf[4][32];

  const int tid = threadIdx.x;
  const int lane = tid & 63;
  const int kw = tid >> 6;             // wave = split-k slot 0..3
  const int ql = lane & 31;
  const int hi = lane >> 5;
  const int bid = blockIdx.x;
  const int c = bid & 7;
  const int r = bid >> 3;              // 0..127
  const int jj = r & 31;               // pair index
  const int bh = c + 8 * (r >> 5);     // 0..31
  const int b = bh >> 4, h = bh & 15;

  const u16* Qf = Qb + (size_t)bh * 64 * 2048;
  const u16* Kf = Kb + (size_t)bh * 64 * 2048;
  const u16* Vf = Vt + (size_t)bh * 64 * 2048;
  const int lofs = lane * 8;

  #pragma unroll 1
  for (int pass = 0; pass < 2; ++pass) {
    const int qt = pass ? (63 - jj) : jj;
    const int qb0 = qt * 32;

    bf16x8 qf[4];
    {
      const u16* qp = Qf + (size_t)qt * 2048 + lofs;
      #pragma unroll
      for (int st = 0; st < 4; ++st) qf[st] = *(const bf16x8*)(qp + st * 512);
    }

    f32x16 ctx0 = {0,0,0,0,0,0,0,0,0,0,0,0,0,0,0,0};
    f32x16 ctx1 = {0,0,0,0,0,0,0,0,0,0,0,0,0,0,0,0};
    float lacc[4] = {0.f, 0.f, 0.f, 0.f};

    bf16x8 kf[4], vf[4];
    if (kw <= qt) {
      // prologue load: tile kw
      {
        const u16* kp = Kf + (size_t)kw * 2048 + lofs;
        const u16* vp = Vf + (size_t)kw * 2048 + lofs;
        #pragma unroll
        for (int st = 0; st < 4; ++st) kf[st] = *(const bf16x8*)(kp + st * 512);
        #pragma unroll
        for (int f = 0; f < 4; ++f) vf[f] = *(const bf16x8*)(vp + f * 512);
      }
      #pragma unroll 2
      for (int t = kw; t <= qt; t += 4) {
        // ---- QK^T (S^T: key-in-reg, q-in-lane) ----
        f32x16 s = {0,0,0,0,0,0,0,0,0,0,0,0,0,0,0,0};
        #pragma unroll
        for (int st = 0; st < 4; ++st)
          s = __builtin_amdgcn_mfma_f32_32x32x16_bf16(kf[st], qf[st], s, 0, 0, 0);

        // prefetch next tile's K (kf dead after QK); clamped reload on last iter
        const int tn = (t + 4 <= qt) ? (t + 4) : qt;
        {
          const u16* kp = Kf + (size_t)tn * 2048 + lofs;
          #pragma unroll
          for (int st = 0; st < 4; ++st) kf[st] = *(const bf16x8*)(kp + st * 512);
        }

        // ---- softmax (fixed max = 0) ----
        float p[16];
        if (t == qt) {  // diagonal tile: causal mask (wave-uniform branch)
          #pragma unroll
          for (int cr = 0; cr < 16; ++cr) {
            const int kl = ((cr & 3) + 8 * (cr >> 2)) + 4 * hi;
            p[cr] = (kl > ql) ? 0.f : fexp2(s[cr]);
          }
        } else {
          #pragma unroll
          for (int cr = 0; cr < 16; ++cr) p[cr] = fexp2(s[cr]);
        }
        #pragma unroll
        for (int cr = 0; cr < 16; ++cr) lacc[cr & 3] += p[cr];

        // ---- PV: fragment k-order baked into V's stored layout ----
        #pragma unroll
        for (int ks = 0; ks < 2; ++ks) {
          uint4 pw;
          pw.x = cvtpk(p[ks * 8 + 0], p[ks * 8 + 1]);
          pw.y = cvtpk(p[ks * 8 + 2], p[ks * 8 + 3]);
          pw.z = cvtpk(p[ks * 8 + 4], p[ks * 8 + 5]);
          pw.w = cvtpk(p[ks * 8 + 6], p[ks * 8 + 7]);
          union { uint4 u; bf16x8 v; } pa; pa.u = pw;
          ctx0 = __builtin_amdgcn_mfma_f32_32x32x16_bf16(vf[ks * 2 + 0], pa.v, ctx0, 0, 0, 0);
          ctx1 = __builtin_amdgcn_mfma_f32_32x32x16_bf16(vf[ks * 2 + 1], pa.v, ctx1, 0, 0, 0);
        }

        // prefetch next tile's V (vf dead after PV)
        {
          const u16* vp = Vf + (size_t)tn * 2048 + lofs;
          #pragma unroll
          for (int f = 0; f < 4; ++f) vf[f] = *(const bf16x8*)(vp + f * 512);
        }
      }
    }

    // ---- 4-way split-k merge (fixed max -> pure addition) ----
    const float lloc = (lacc[0] + lacc[1]) + (lacc[2] + lacc[3]);
    const float lwv = lloc + swap32f(lloc);

    // write partial ctx: chunk ch = d/4, stored at ch ^ (q&15) (bank-conflict-free)
    #pragma unroll
    for (int grp = 0; grp < 4; ++grp) {
      const int ch = grp * 2 + hi;
      f32x4 t0 = {ctx0[grp * 4 + 0], ctx0[grp * 4 + 1], ctx0[grp * 4 + 2], ctx0[grp * 4 + 3]};
      f32x4 t1 = {ctx1[grp * 4 + 0], ctx1[grp * 4 + 1], ctx1[grp * 4 + 2], ctx1[grp * 4 + 3]};
      *(f32x4*)&mbuf[kw][ql][(ch ^ ql) * 4 & 63]       = t0;
      *(f32x4*)&mbuf[kw][ql][((ch + 8) ^ ql) * 4 & 63] = t1;
    }
    if (lane < 32) lbuf[kw][ql] = lwv;
    __syncthreads();

    // each wave sums d-slice [kw*16 + hi*8, +8) over the 4 partials
    {
      const int ch0 = kw * 4 + hi * 2;
      f32x4 a0 = {0.f, 0.f, 0.f, 0.f}, a1 = {0.f, 0.f, 0.f, 0.f};
      #pragma unroll
      for (int p2 = 0; p2 < 4; ++p2) {
        a0 += *(const f32x4*)&mbuf[p2][ql][(ch0 ^ ql) * 4 & 63];
        a1 += *(const f32x4*)&mbuf[p2][ql][((ch0 + 1) ^ ql) * 4 & 63];
      }
      const float lt = (lbuf[0][ql] + lbuf[1][ql]) + (lbuf[2][ql] + lbuf[3][ql]);
      const float inv = __builtin_amdgcn_rcpf(lt);
      uint4 pw;
      pw.x = cvtpk(a0[0] * inv, a0[1] * inv);
      pw.y = cvtpk(a0[2] * inv, a0[3] * inv);
      pw.z = cvtpk(a1[0] * inv, a1[1] * inv);
      pw.w = cvtpk(a1[2] * inv, a1[3] * inv);
      *(uint4*)(Ctx + (size_t)(b * SEQ + qb0 + ql) * 1024 + h * 64 + kw * 16 + hi * 8) = pw;
    }
    __syncthreads();  // protect mbuf/lbuf reuse in next pass
  }
}

// ---------------- 4) output projection + bias (fp32 out; r10, unchanged) ----------------
__device__ __forceinline__ void out_compute(
    const u16* __restrict__ AsB, const u16* __restrict__ BsB,
    int wr, int wc, int g, int lm, f32x4 acc[4][4]) {
  #pragma unroll
  for (int kk = 0; kk < 2; ++kk) {
    const int slot = ((kk * 4 + g) ^ (lm & 7)) << 3;
    bf16x8 af[4], bf[4];
    #pragma unroll
    for (int i = 0; i < 4; ++i)
      af[i] = *(const bf16x8*)(AsB + (wr * 64 + i * 16 + lm) * 64 + slot);
    #pragma unroll
    for (int n = 0; n < 4; ++n)
      bf[n] = *(const bf16x8*)(BsB + (wc * 64 + n * 16 + lm) * 64 + slot);
    #pragma unroll
    for (int i = 0; i < 4; ++i)
      #pragma unroll
      for (int n = 0; n < 4; ++n)
        acc[i][n] = __builtin_amdgcn_mfma_f32_16x16x32_bf16(af[i], bf[n], acc[i][n], 0, 0, 0);
  }
}

__global__ __launch_bounds__(256)
void gemm_out_kernel(const u16* __restrict__ Ctx, const u16* __restrict__ WoT,
                     const float* __restrict__ bo, float* __restrict__ out) {
  __shared__ u16 As[2][128 * 64];  // 32 KB
  __shared__ u16 Bs[2][128 * 64];  // 32 KB
  const int tid = threadIdx.x;
  const int lane = tid & 63;
  const int w = tid >> 6;
  const int bm = blockIdx.x * 128;
  const int bn = blockIdx.y * 128;
  const int wr = w >> 1, wc = w & 1;
  const int g = lane >> 4, lm = lane & 15;

  const int r_in = lane >> 3;
  const int s_w = lane & 7;
  const int swz_col = (s_w ^ r_in) << 3;

  const int c0 = w * 4;
  const u16* a_src = Ctx + (size_t)(bm + c0 * 8 + r_in) * D_IN + swz_col;
  const u16* b_src = WoT + (size_t)(bn + c0 * 8 + r_in) * D_IN + swz_col;

#define OUT_STAGE(BUF, K0)                                              \
  do {                                                                  \
    _Pragma("unroll")                                                   \
    for (int j = 0; j < 4; ++j) {                                       \
      GLD_LDS16(a_src + j * 8 * D_IN + (K0), &As[BUF][(c0 + j) * 512]); \
      GLD_LDS16(b_src + j * 8 * D_IN + (K0), &Bs[BUF][(c0 + j) * 512]); \
    }                                                                   \
  } while (0)

  f32x4 acc[4][4];
  #pragma unroll
  for (int i = 0; i < 4; ++i)
    #pragma unroll
    for (int n = 0; n < 4; ++n) acc[i][n] = {0.f, 0.f, 0.f, 0.f};

  OUT_STAGE(0, 0);
  OUT_STAGE(1, 64);
  #pragma unroll 1
  for (int tt = 0; tt < 7; ++tt) {
    asm volatile("s_waitcnt vmcnt(8)" ::: "memory");
    __builtin_amdgcn_s_barrier();
    out_compute(As[0], Bs[0], wr, wc, g, lm, acc);
    __builtin_amdgcn_s_barrier();
    OUT_STAGE(0, (2 * tt + 2) * 64);
    asm volatile("s_waitcnt vmcnt(8)" ::: "memory");
    __builtin_amdgcn_s_barrier();
    out_compute(As[1], Bs[1], wr, wc, g, lm, acc);
    __builtin_amdgcn_s_barrier();
    OUT_STAGE(1, (2 * tt + 3) * 64);
  }
  asm volatile("s_waitcnt vmcnt(8)" ::: "memory");
  __builtin_amdgcn_s_barrier();
  out_compute(As[0], Bs[0], wr, wc, g, lm, acc);  // t=14
  asm volatile("s_waitcnt vmcnt(0)" ::: "memory");
  __builtin_amdgcn_s_barrier();
  out_compute(As[1], Bs[1], wr, wc, g, lm, acc);  // t=15
#undef OUT_STAGE

  #pragma unroll
  for (int i = 0; i < 4; ++i)
    #pragma unroll
    for (int n = 0; n < 4; ++n)
      #pragma unroll
      for (int r = 0; r < 4; ++r) {
        const int m = bm + wr * 64 + i * 16 + g * 4 + r;
        const int cidx = bn + wc * 64 + n * 16 + lm;
        out[(size_t)m * 1024 + cidx] = acc[i][n][r] + bo[cidx];
      }
}

extern "C" void kernel_launch(void* const* d_in, const int* in_sizes, int n_in,
                              void* d_out, int out_size, void* d_ws, size_t ws_size,
                              hipStream_t stream) {
  (void)in_sizes; (void)n_in; (void)out_size; (void)ws_size;
  const float* x  = (const float*)d_in[0];
  const float* Wq = (const float*)d_in[1];
  const float* Wk = (const float*)d_in[2];
  const float* Wv = (const float*)d_in[3];
  const float* Wo = (const float*)d_in[4];
  const float* bo = (const float*)d_in[5];
  float* out = (float*)d_out;

  char* ws = (char*)d_ws;
  u16* xb  = (u16*)(ws);
  u16* WqT = (u16*)(ws + (8u << 20));
  u16* WkT = (u16*)(ws + (10u << 20));
  u16* WvT = (u16*)(ws + (12u << 20));
  u16* WoT = (u16*)(ws + (14u << 20));
  u16* Qb  = (u16*)(ws + (16u << 20));
  u16* Kb  = (u16*)(ws + (24u << 20));
  u16* Vt  = (u16*)(ws + (32u << 20));
  u16* Ctx = xb;  // xb fully consumed by gemm_qkv before attn writes Ctx

  prep_kernel<<<dim3(8192), 256, 0, stream>>>(x, xb, Wq, Wk, Wv, Wo, WqT, WkT, WvT, WoT);
  gemm_qkv_kernel<<<dim3(32, 8), 512, 0, stream>>>(xb, WqT, WkT, WvT, Qb, Kb, Vt);
  attn4_kernel<<<dim3(1024), 256, 0, stream>>>(Qb, Kb, Vt, Ctx);
  gemm_out_kernel<<<dim3(32, 8), 256, 0, stream>>>(Ctx, WoT, bo, out);
}